// Round 9
// baseline (333.893 us; speedup 1.0000x reference)
//
#include <hip/hip_runtime.h>
#include <hip/hip_bf16.h>

#define HID    1024
#define NBATCH 32
#define SRC    2048
#define MROWS  (NBATCH * SRC)   // 65536

typedef _Float16 f16;
typedef f16   f16x8 __attribute__((ext_vector_type(8)));
typedef f16   f16x4 __attribute__((ext_vector_type(4)));
typedef float f32x4 __attribute__((ext_vector_type(4)));

#define BAR()    __builtin_amdgcn_s_barrier()
#define LGKM0()  asm volatile("s_waitcnt lgkmcnt(0)" ::: "memory")
#define SCHED0() __builtin_amdgcn_sched_barrier(0)
#define VMCM(n)  asm volatile("s_waitcnt vmcnt(" #n ")" ::: "memory")

__device__ __forceinline__ void gload_lds16(const void* g, void* l) {
  __builtin_amdgcn_global_load_lds(
      (const __attribute__((address_space(1))) void*)g,
      (__attribute__((address_space(3))) void*)l, 16, 0, 0);
}

__device__ __forceinline__ float fast_tanh(float x) {
  x = fminf(fmaxf(x, -15.f), 15.f);
  float e = __expf(2.f * x);
  return (e - 1.f) / (e + 1.f);
}

// ---------------------------------------------------------------- kernel 1
__global__ void convw_k(const float* __restrict__ attn_w, f16* __restrict__ Wf) {
  int idx = blockIdx.x * 256 + threadIdx.x;
  int j = idx * 4;
  int o = j >> 10, h = j & 1023;
  f32x4 d = *(const f32x4*)(attn_w + (size_t)o * 2048 + HID + h);
  f16x4 q = { (f16)d[0], (f16)d[1], (f16)d[2], (f16)d[3] };
  *(f16x4*)(Wf + (size_t)o * HID + h) = q;
}

// ---------------------------------------------------------------- kernel 2
__global__ void hvec_k(const float* __restrict__ hidden,
                       const float* __restrict__ attn_w,
                       const float* __restrict__ attn_b,
                       float* __restrict__ hvec) {
  int idx = blockIdx.x * 256 + threadIdx.x;
  int b = idx >> 10, o = idx & 1023;
  const float* wrow = attn_w + (size_t)o * 2048;
  const float* hrow = hidden + (size_t)b * HID;
  float acc = 0.f;
  for (int h = 0; h < HID; h += 4) {
    f32x4 wv = *(const f32x4*)(wrow + h);
    f32x4 hv = *(const f32x4*)(hrow + h);
    acc += wv[0]*hv[0] + wv[1]*hv[1] + wv[2]*hv[2] + wv[3]*hv[3];
  }
  hvec[idx] = acc + attn_b[o];
}

// ---------------------------------------------------------------- kernel 3
// BM=BN=256, BK=64, 8 waves (2M x 4N, per-wave 128x64), 128 KB dbuf LDS.
// FUSED A-CONVERSION (no convA pre-pass): A staged f32 global -> regs (one
// tile ahead) -> cvt f16 -> ds_write_b128 into the same swizzled linear
// layout global_load_lds would produce. B staged via global_load_lds (L2-hot).
// Ledger per tile T (in-flight counts exact, verified):
//   enter T: only IA(T+1)=8 outstanding -> VMCM(0) is EXACT (no drain loss)
//   issue IB(T+1)=4 gload_lds, IA(T+2)=8 reg loads
//   end T:  VMCM(8) retires IB(T+1); IA(T+2) stays in flight across barrier.
// Zigzag quads (0,0)(0,1)(1,1)(1,0): every fragment read from LDS once.

#define IB4(Tn) do { \
  _Pragma("unroll") for (int q_ = 0; q_ < 4; ++q_) \
    gload_lds16(Bb + (size_t)(q_ * 64 + (tid >> 3)) * HID + (Tn) * 64 + scol, \
                lds + ((Tn) & 1) * 65536 + 32768 + q_ * 8192 + w * 1024); } while (0)

#define IA8(Tn) do { \
  _Pragma("unroll") for (int q_ = 0; q_ < 4; ++q_) { \
    const float* p_ = A32 + (size_t)(q_ * 64 + (tid >> 3)) * HID + (Tn) * 64 + scol; \
    rA[q_ * 2]     = *(const f32x4*)p_; \
    rA[q_ * 2 + 1] = *(const f32x4*)(p_ + 4); } } while (0)

// write exactly where gload_lds would have: u*8192 + tid*16 (linear), so the
// swizzle (pre-swizzled source col 'scol') and read-side XOR stay valid.
#define CV8(Tn) do { \
  _Pragma("unroll") for (int q_ = 0; q_ < 4; ++q_) { \
    f16x8 h_ = { (f16)rA[q_*2][0], (f16)rA[q_*2][1], (f16)rA[q_*2][2], (f16)rA[q_*2][3], \
                 (f16)rA[q_*2+1][0], (f16)rA[q_*2+1][1], (f16)rA[q_*2+1][2], (f16)rA[q_*2+1][3] }; \
    *(f16x8*)(lds + ((Tn) & 1) * 65536 + q_ * 8192 + tid * 16) = h_; } } while (0)

#define RD_A(la_, mh_) do { \
  _Pragma("unroll") for (int m4 = 0; m4 < 4; ++m4) { \
    const char* rb = (la_) + (wr * 128 + (mh_) * 64 + m4 * 16 + lr) * 128; \
    aF[m4][0] = *(const f16x8*)(rb + ((lg ^ sw) << 4)); \
    aF[m4][1] = *(const f16x8*)(rb + (((4 + lg) ^ sw) << 4)); } } while (0)

#define RD_B(lb_, dst, nh_) do { \
  _Pragma("unroll") for (int n2 = 0; n2 < 2; ++n2) { \
    const char* rb = (lb_) + (wc * 64 + (nh_) * 32 + n2 * 16 + lr) * 128; \
    dst[n2][0] = *(const f16x8*)(rb + ((lg ^ sw) << 4)); \
    dst[n2][1] = *(const f16x8*)(rb + (((4 + lg) ^ sw) << 4)); } } while (0)

#define MFMA16(bsrc, mh_, nh_) do { \
  __builtin_amdgcn_s_setprio(1); \
  _Pragma("unroll") for (int ks = 0; ks < 2; ++ks) \
  _Pragma("unroll") for (int m4 = 0; m4 < 4; ++m4) \
  _Pragma("unroll") for (int n2 = 0; n2 < 2; ++n2) \
    acc[(mh_) * 4 + m4][(nh_) * 2 + n2] = __builtin_amdgcn_mfma_f32_16x16x32_f16( \
        aF[m4][ks], bsrc[n2][ks], acc[(mh_) * 4 + m4][(nh_) * 2 + n2], 0, 0, 0); \
  __builtin_amdgcn_s_setprio(0); } while (0)

#define TILE_STD(T_) do { \
  const char* la_ = lds + ((T_) & 1) * 65536; \
  const char* lb_ = la_ + 32768; \
  VMCM(0); SCHED0(); \
  CV8((T_) + 1); \
  IB4((T_) + 1); \
  IA8((T_) + 2); \
  RD_A(la_, 0); RD_B(lb_, bF0, 0); \
  MFMA16(bF0, 0, 0); \
  RD_B(lb_, bF1, 1); \
  MFMA16(bF1, 0, 1); \
  RD_A(la_, 1); \
  MFMA16(bF1, 1, 1); \
  MFMA16(bF0, 1, 0); \
  VMCM(8); LGKM0(); SCHED0(); BAR(); \
} while (0)

__global__ __launch_bounds__(512, 2) void gemm_f16(
    const float* __restrict__ A32f,  // (65536, 1024) f32 encoder outputs
    const f16*  __restrict__ Wf,     // (1024, 1024) f16
    const float* __restrict__ hvec,  // (32, 1024)
    const float* __restrict__ v,     // (1024)
    float* __restrict__ part)        // (4, MROWS)
{
  extern __shared__ __align__(16) char lds[];   // 131072 = 2 x (A 32K + B 32K)

  int bid = blockIdx.x;                   // 1024 blocks
  int wg = (bid & 7) * 128 + (bid >> 3);  // bijective XCD-chunked swizzle
  int m_idx = wg >> 2, n_idx = wg & 3;    // 4 n-tiles share one A panel per XCD L2
  long row0 = (long)m_idx * 256;
  int o0 = n_idx * 256;
  int b = (int)(row0 >> 11);

  int tid = threadIdx.x;
  int l = tid & 63, w = tid >> 6;         // 8 waves
  int wr = w >> 2, wc = w & 3;            // 2 (M) x 4 (N); per-wave 128 x 64
  int lr = l & 15, lg = l >> 4;
  int sw = lr & 7;                        // ds_read-side 16B-slot XOR
  int scol = ((tid & 7) ^ ((tid >> 3) & 7)) * 8;  // pre-swizzled col (elems)

  const float* A32 = A32f + row0 * HID;
  const f16*   Bb  = Wf + (size_t)o0 * HID;

  f32x4 acc[8][4];
#pragma unroll
  for (int m = 0; m < 8; ++m)
#pragma unroll
    for (int n = 0; n < 4; ++n) acc[m][n] = (f32x4){0.f, 0.f, 0.f, 0.f};

  f32x4 rA[8];
  f16x8 aF[4][2], bF0[2][2], bF1[2][2];

  // ---- prologue: B(0) dma + A(0) regs; cvt+write A(0); issue A(1) regs
  IB4(0);
  IA8(0);
  VMCM(0); SCHED0();
  CV8(0);
  IA8(1);                                  // 8 in flight across barrier
  LGKM0(); SCHED0(); BAR();

  // ---- tiles 0..13 steady
#pragma unroll 1
  for (int E = 0; E < 14; E += 2) {
    TILE_STD(E);
    TILE_STD(E + 1);
  }
  // ---- tile 14: stage only B(15)+cvt A(15); no IA(16)
  {
    const char* la_ = lds;                 // 14 & 1 == 0
    const char* lb_ = la_ + 32768;
    VMCM(0); SCHED0();
    CV8(15);
    IB4(15);
    RD_A(la_, 0); RD_B(lb_, bF0, 0);
    MFMA16(bF0, 0, 0);
    RD_B(lb_, bF1, 1);
    MFMA16(bF1, 0, 1);
    RD_A(la_, 1);
    MFMA16(bF1, 1, 1);
    MFMA16(bF0, 1, 0);
    VMCM(0); LGKM0(); SCHED0(); BAR();
  }
  // ---- tile 15: compute only
  {
    const char* la_ = lds + 65536;
    const char* lb_ = la_ + 32768;
    RD_A(la_, 0); RD_B(lb_, bF0, 0);
    MFMA16(bF0, 0, 0);
    RD_B(lb_, bF1, 1);
    MFMA16(bF1, 0, 1);
    RD_A(la_, 1);
    MFMA16(bF1, 1, 1);
    MFMA16(bF0, 1, 0);
  }

  // ---- fused epilogue: tanh(C + hvec) . v reduced over this block's 256 o's
  float hvv[4], vvv[4];
#pragma unroll
  for (int n = 0; n < 4; ++n) {
    int o = o0 + wc * 64 + n * 16 + lr;
    hvv[n] = hvec[b * HID + o];
    vvv[n] = v[o];
  }
  float* scf = (float*)lds;
  __syncthreads();
#pragma unroll
  for (int m = 0; m < 8; ++m) {
#pragma unroll
    for (int r = 0; r < 4; ++r) {
      float s = 0.f;
#pragma unroll
      for (int n = 0; n < 4; ++n)
        s += fast_tanh(acc[m][n][r] + hvv[n]) * vvv[n];
      s += __shfl_xor(s, 1); s += __shfl_xor(s, 2);
      s += __shfl_xor(s, 4); s += __shfl_xor(s, 8);
      if (lr == 0) scf[wc * 256 + wr * 128 + m * 16 + lg * 4 + r] = s;
    }
  }
  __syncthreads();
  if (tid < 256)
    part[(size_t)n_idx * MROWS + row0 + tid] =
        scf[tid] + scf[256 + tid] + scf[512 + tid] + scf[768 + tid];
}

// ---------------------------------------------------------------- kernel 4
__global__ void softmax_k(const float* __restrict__ part, float* __restrict__ out,
                          int nsl) {
  int b = blockIdx.x;
  __shared__ float srow[SRC];
  __shared__ float red[8];
  int tid = threadIdx.x;  // 256

  float lmax = -1e30f;
  for (int i = tid; i < SRC; i += 256) {
    float s = 0.f;
    for (int t = 0; t < nsl; ++t)
      s += part[(size_t)t * MROWS + (size_t)b * SRC + i];
    srow[i] = s;
    lmax = fmaxf(lmax, s);
  }
#pragma unroll
  for (int off = 32; off >= 1; off >>= 1)
    lmax = fmaxf(lmax, __shfl_xor(lmax, off));
  if ((tid & 63) == 0) red[tid >> 6] = lmax;
  __syncthreads();
  float bmax = fmaxf(fmaxf(red[0], red[1]), fmaxf(red[2], red[3]));

  float lsum = 0.f;
  for (int i = tid; i < SRC; i += 256) {
    float e = __expf(srow[i] - bmax);
    srow[i] = e;
    lsum += e;
  }
#pragma unroll
  for (int off = 32; off >= 1; off >>= 1)
    lsum += __shfl_xor(lsum, off);
  if ((tid & 63) == 0) red[4 + (tid >> 6)] = lsum;
  __syncthreads();
  float inv = 1.f / (red[4] + red[5] + red[6] + red[7]);
  for (int i = tid; i < SRC; i += 256)
    out[(size_t)b * SRC + i] = srow[i] * inv;
}

// ---------------------------------------------------------------- launch
extern "C" void kernel_launch(void* const* d_in, const int* in_sizes, int n_in,
                              void* d_out, int out_size, void* d_ws, size_t ws_size,
                              hipStream_t stream) {
  const float* hidden = (const float*)d_in[0];
  const float* enc    = (const float*)d_in[1];
  const float* attn_w = (const float*)d_in[2];
  const float* attn_b = (const float*)d_in[3];
  const float* v      = (const float*)d_in[4];
  float* out = (float*)d_out;

  char* ws = (char*)d_ws;
  f16*   Wf   = (f16*)ws;                                     // 2 MB @ 0
  float* hv   = (float*)(ws + (2ull << 20));                  // 128 KB
  float* part = (float*)(ws + (2ull << 20) + (128ull << 10)); // 1 MB (4 slices)

  convw_k<<<1024, 256, 0, stream>>>(attn_w, Wf);
  hvec_k <<<128,  256, 0, stream>>>(hidden, attn_w, attn_b, hv);
  gemm_f16<<<1024, 512, 131072, stream>>>(enc, Wf, hv, v, part);
  softmax_k<<<NBATCH, 256, 0, stream>>>(part, out, 4);
}